// Round 5
// baseline (378.891 us; speedup 1.0000x reference)
//
#include <hip/hip_runtime.h>
#include <hip/hip_bf16.h>

// NNConv on MI355X. msg[E x 32] = Z[E x 4096] @ w2r[4096 x 32],
// Z[e, c*32+i] = h[e,c]*xs[e,i] built on the fly in A-fragments (packed muls).
// Round 5: 128 edges/wave (4 edge-groups -> B-fragment reuse x4, 4 indep acc
// chains), 2-wave blocks (256 edges, 1563 blocks, 3 blocks/CU at 48 KB LDS,
// 2.03 scheduling rounds), v_pk_mul_f32 Z-gen, 8c double-buffered w2 chunks.

#define NN 25000
#define EE 400000

typedef __bf16 bf16x8 __attribute__((ext_vector_type(8)));
typedef float  f32x16 __attribute__((ext_vector_type(16)));

__device__ __forceinline__ float2 mul2(float2 a, float2 b) {
    return make_float2(a.x * b.x, a.y * b.y);   // -> v_pk_mul_f32
}

// ---------------- prep: pack w1/w2/b2 to fragment layout + zero replicas ----------------
__global__ __launch_bounds__(256) void prep_kernel(
    const float* __restrict__ w1, const float* __restrict__ w2,
    const float* __restrict__ b2,
    __bf16* __restrict__ w2p, __bf16* __restrict__ w1p, __bf16* __restrict__ b2p,
    float4* __restrict__ part4, int nzero4)
{
    int b = blockIdx.x;
    if (b < 532) {                       // 532*256 = 136192 pack threads, exact
        int t = b * 256 + threadIdx.x;
        if (t < 131072) {
            int j = t & 7, lane = (t >> 3) & 63, ih = (t >> 9) & 1, c = t >> 10;
            w2p[t] = (__bf16)w2[c * 1024 + (ih * 16 + ((lane >> 5) << 3) + j) * 32 + (lane & 31)];
        } else if (t < 135168) {
            int u = t - 131072;
            int j = u & 7, lane = (u >> 3) & 63, kk = (u >> 9) & 1, r = u >> 10;
            w1p[u] = (__bf16)w1[(kk * 16 + ((lane >> 5) << 3) + j) * 128 + r * 32 + (lane & 31)];
        } else {
            int u = t - 135168;
            int j = u & 7, lane = (u >> 3) & 63, ih = u >> 9;
            b2p[u] = (__bf16)b2[(ih * 16 + ((lane >> 5) << 3) + j) * 32 + (lane & 31)];
        }
    } else {
        int z = (b - 532) * 256 + threadIdx.x;
        if (z < nzero4) part4[z] = make_float4(0.f, 0.f, 0.f, 0.f);
    }
}

// ---------------- final: out = x@root + bias + sum(replicas) ----------------
__global__ __launch_bounds__(256) void final_kernel(
    const float* __restrict__ x, const float* __restrict__ root,
    const float* __restrict__ bias, const float* __restrict__ part,
    int ncopies, float* __restrict__ out)
{
    int gid = blockIdx.x * 256 + threadIdx.x;   // exactly NN*32
    int n = gid >> 5, o = gid & 31;
    float acc = bias[o];
    const float* xr = x + (n << 5);
#pragma unroll
    for (int i = 0; i < 32; ++i)
        acc = fmaf(xr[i], root[(i << 5) + o], acc);
    for (int c = 0; c < ncopies; ++c) acc += part[(size_t)c * 800000 + gid];
    out[gid] = acc;
}

// ---------------- fused MFMA edge kernel ----------------
// 128 thr = 2 waves x 128 edges (4 groups of 32) = 256 edges/block, 1563 blocks.
__global__ __launch_bounds__(128, 2) void edge_kernel(
    const float*  __restrict__ x,
    const int*    __restrict__ ei,
    const float*  __restrict__ ea,
    const float*  __restrict__ b1,
    const __bf16* __restrict__ w2p,
    const __bf16* __restrict__ w1p,
    const __bf16* __restrict__ b2p,
    float* __restrict__ outp, int copyMask)
{
    __shared__ __align__(16) __bf16 w2c[2][8192];          // 2 x 16 KB (8c chunks)
    __shared__ unsigned int hTp[2][32][32][2];             // 16 KB: packed h, 4 groups/entry

    const int t    = threadIdx.x;
    const int w    = t >> 6;
    const int lane = t & 63;
    const int l    = lane & 31;
    const int half = lane >> 5;

    const int  ebraw = blockIdx.x * 256 + w * 128;
    const bool live  = (ebraw + 128) <= EE;                // wave-uniform
    const int  ebw   = live ? ebraw : (EE - 128);

    float* __restrict__ myout = outp + (size_t)(blockIdx.x & copyMask) * 800000;

    // ---- gather xs rows for 4 edge-groups (float2 pairs, i = ih*16+half*8+2p..) ----
    float2 xs0[8], xs1[8], xs2[8], xs3[8];
    {
        int s0 = ei[ebw + l], s1 = ei[ebw + 32 + l];
        int s2 = ei[ebw + 64 + l], s3 = ei[ebw + 96 + l];
#pragma unroll
        for (int ih = 0; ih < 2; ++ih) {
            float4 a0, a1;
            a0 = *(const float4*)(x + s0 * 32 + ih * 16 + half * 8);
            a1 = *(const float4*)(x + s0 * 32 + ih * 16 + half * 8 + 4);
            xs0[ih*4+0] = make_float2(a0.x, a0.y); xs0[ih*4+1] = make_float2(a0.z, a0.w);
            xs0[ih*4+2] = make_float2(a1.x, a1.y); xs0[ih*4+3] = make_float2(a1.z, a1.w);
            a0 = *(const float4*)(x + s1 * 32 + ih * 16 + half * 8);
            a1 = *(const float4*)(x + s1 * 32 + ih * 16 + half * 8 + 4);
            xs1[ih*4+0] = make_float2(a0.x, a0.y); xs1[ih*4+1] = make_float2(a0.z, a0.w);
            xs1[ih*4+2] = make_float2(a1.x, a1.y); xs1[ih*4+3] = make_float2(a1.z, a1.w);
            a0 = *(const float4*)(x + s2 * 32 + ih * 16 + half * 8);
            a1 = *(const float4*)(x + s2 * 32 + ih * 16 + half * 8 + 4);
            xs2[ih*4+0] = make_float2(a0.x, a0.y); xs2[ih*4+1] = make_float2(a0.z, a0.w);
            xs2[ih*4+2] = make_float2(a1.x, a1.y); xs2[ih*4+3] = make_float2(a1.z, a1.w);
            a0 = *(const float4*)(x + s3 * 32 + ih * 16 + half * 8);
            a1 = *(const float4*)(x + s3 * 32 + ih * 16 + half * 8 + 4);
            xs3[ih*4+0] = make_float2(a0.x, a0.y); xs3[ih*4+1] = make_float2(a0.z, a0.w);
            xs3[ih*4+2] = make_float2(a1.x, a1.y); xs3[ih*4+3] = make_float2(a1.z, a1.w);
        }
    }

    f32x16 acc0, acc1, acc2, acc3;
#pragma unroll
    for (int i = 0; i < 16; ++i) { acc0[i]=0.f; acc1[i]=0.f; acc2[i]=0.f; acc3[i]=0.f; }

    // ---- phase-1 slice: h[r*32..r*32+32) for all 4 groups, wave-private hTp ----
    auto phase1 = [&](int r) {
        bf16x8 w1f0 = *(const bf16x8*)(w1p + ((r * 2 + 0) * 64 + lane) * 8);
        bf16x8 w1f1 = *(const bf16x8*)(w1p + ((r * 2 + 1) * 64 + lane) * 8);
#pragma unroll
        for (int pair = 0; pair < 2; ++pair) {
            f32x16 hA, hB;
#pragma unroll
            for (int i = 0; i < 16; ++i) { hA[i] = 0.f; hB[i] = 0.f; }
#pragma unroll
            for (int kk = 0; kk < 2; ++kk) {
                union { bf16x8 v; __hip_bfloat162 h2[4]; } fA, fB;
                const float* pA = ea + (ebw + (pair*2+0)*32 + l) * 32 + kk*16 + half*8;
                const float* pB = ea + (ebw + (pair*2+1)*32 + l) * 32 + kk*16 + half*8;
                float4 a0 = *(const float4*)pA, a1 = *(const float4*)(pA + 4);
                float4 c0 = *(const float4*)pB, c1 = *(const float4*)(pB + 4);
                fA.h2[0] = __float22bfloat162_rn(make_float2(a0.x, a0.y));
                fA.h2[1] = __float22bfloat162_rn(make_float2(a0.z, a0.w));
                fA.h2[2] = __float22bfloat162_rn(make_float2(a1.x, a1.y));
                fA.h2[3] = __float22bfloat162_rn(make_float2(a1.z, a1.w));
                fB.h2[0] = __float22bfloat162_rn(make_float2(c0.x, c0.y));
                fB.h2[1] = __float22bfloat162_rn(make_float2(c0.z, c0.w));
                fB.h2[2] = __float22bfloat162_rn(make_float2(c1.x, c1.y));
                fB.h2[3] = __float22bfloat162_rn(make_float2(c1.z, c1.w));
                bf16x8 wf = kk ? w1f1 : w1f0;
                hA = __builtin_amdgcn_mfma_f32_32x32x16_bf16(wf, fA.v, hA, 0, 0, 0);
                hB = __builtin_amdgcn_mfma_f32_32x32x16_bf16(wf, fB.v, hB, 0, 0, 0);
            }
#pragma unroll
            for (int i = 0; i < 16; ++i) {
                int row = (i & 3) + ((i >> 2) << 3) + (half << 2);
                float bb = b1[r * 32 + row];
                __hip_bfloat162 pk = __float22bfloat162_rn(
                    make_float2(fmaxf(hA[i] + bb, 0.f), fmaxf(hB[i] + bb, 0.f)));
                hTp[w][row][l][pair] = *(unsigned int*)&pk;
            }
        }
    };

    // ---- w2 chunk pipeline prologue: chunk0 -> buf0, pf holds chunk1 ----
    const char* w2g = (const char*)w2p;
    float4 pf[8];
#pragma unroll
    for (int s = 0; s < 8; ++s)
        pf[s] = *(const float4*)(w2g + s * 2048 + t * 16);
#pragma unroll
    for (int s = 0; s < 8; ++s)
        ((float4*)w2c[0])[t + s * 128] = pf[s];
#pragma unroll
    for (int s = 0; s < 8; ++s)
        pf[s] = *(const float4*)(w2g + 16384 + s * 2048 + t * 16);
    phase1(0);
    __syncthreads();

    // chunk body: write pf(cc+1)->WB, issue pf loads (cc+2), compute RB, barrier
    auto chunk = [&](int cc, const __bf16* RB, __bf16* WBp) {
        if (cc < 15) {
            float4* WB = (float4*)WBp;
#pragma unroll
            for (int s = 0; s < 8; ++s) WB[t + s * 128] = pf[s];
        }
        if (cc < 14) {
#pragma unroll
            for (int s = 0; s < 8; ++s)
                pf[s] = *(const float4*)(w2g + (cc + 2) * 16384 + s * 2048 + t * 16);
        }
#pragma unroll
        for (int cl = 0; cl < 8; ++cl) {
            const uint2 u = *(const uint2*)&hTp[w][((cc & 3) << 3) + cl][l][0];
            float2 hv0 = make_float2(__uint_as_float(u.x << 16),        __uint_as_float(u.x << 16));
            float2 hv1 = make_float2(__uint_as_float(u.x & 0xffff0000u),__uint_as_float(u.x & 0xffff0000u));
            float2 hv2 = make_float2(__uint_as_float(u.y << 16),        __uint_as_float(u.y << 16));
            float2 hv3 = make_float2(__uint_as_float(u.y & 0xffff0000u),__uint_as_float(u.y & 0xffff0000u));
#pragma unroll
            for (int ih = 0; ih < 2; ++ih) {
                bf16x8 bfr = *(const bf16x8*)(RB + (((cl << 1) + ih) * 64 + lane) * 8);
                union { bf16x8 v; __hip_bfloat162 h2[4]; } A;
#pragma unroll
                for (int p = 0; p < 4; ++p)
                    A.h2[p] = __float22bfloat162_rn(mul2(hv0, xs0[ih*4+p]));
                acc0 = __builtin_amdgcn_mfma_f32_32x32x16_bf16(A.v, bfr, acc0, 0, 0, 0);
#pragma unroll
                for (int p = 0; p < 4; ++p)
                    A.h2[p] = __float22bfloat162_rn(mul2(hv1, xs1[ih*4+p]));
                acc1 = __builtin_amdgcn_mfma_f32_32x32x16_bf16(A.v, bfr, acc1, 0, 0, 0);
#pragma unroll
                for (int p = 0; p < 4; ++p)
                    A.h2[p] = __float22bfloat162_rn(mul2(hv2, xs2[ih*4+p]));
                acc2 = __builtin_amdgcn_mfma_f32_32x32x16_bf16(A.v, bfr, acc2, 0, 0, 0);
#pragma unroll
                for (int p = 0; p < 4; ++p)
                    A.h2[p] = __float22bfloat162_rn(mul2(hv3, xs3[ih*4+p]));
                acc3 = __builtin_amdgcn_mfma_f32_32x32x16_bf16(A.v, bfr, acc3, 0, 0, 0);
            }
        }
        __syncthreads();
    };

#pragma unroll 1
    for (int r = 0; r < 4; ++r) {
        if (r > 0) phase1(r);                 // wave-private hTp: no barrier needed
        chunk(r * 4 + 0, w2c[0], w2c[1]);
        chunk(r * 4 + 1, w2c[1], w2c[0]);
        chunk(r * 4 + 2, w2c[0], w2c[1]);
        chunk(r * 4 + 3, w2c[1], w2c[0]);
    }

    // ---- b2 contribution: one extra K-step with h == 1 ----
#pragma unroll
    for (int ih = 0; ih < 2; ++ih) {
        bf16x8 bfr = *(const bf16x8*)(b2p + (ih * 64 + lane) * 8);
        union { bf16x8 v; __hip_bfloat162 h2[4]; } A;
#pragma unroll
        for (int p = 0; p < 4; ++p) A.h2[p] = __float22bfloat162_rn(xs0[ih*4+p]);
        acc0 = __builtin_amdgcn_mfma_f32_32x32x16_bf16(A.v, bfr, acc0, 0, 0, 0);
#pragma unroll
        for (int p = 0; p < 4; ++p) A.h2[p] = __float22bfloat162_rn(xs1[ih*4+p]);
        acc1 = __builtin_amdgcn_mfma_f32_32x32x16_bf16(A.v, bfr, acc1, 0, 0, 0);
#pragma unroll
        for (int p = 0; p < 4; ++p) A.h2[p] = __float22bfloat162_rn(xs2[ih*4+p]);
        acc2 = __builtin_amdgcn_mfma_f32_32x32x16_bf16(A.v, bfr, acc2, 0, 0, 0);
#pragma unroll
        for (int p = 0; p < 4; ++p) A.h2[p] = __float22bfloat162_rn(xs3[ih*4+p]);
        acc3 = __builtin_amdgcn_mfma_f32_32x32x16_bf16(A.v, bfr, acc3, 0, 0, 0);
    }

    // ---- scatter (skip for clamped tail waves) ----
    if (live) {
#pragma unroll
        for (int i = 0; i < 16; ++i) {
            int el = (i & 3) + ((i >> 2) << 3) + (half << 2);
            atomicAdd(myout + ei[EE + ebw +      el] * 32 + l, acc0[i]);
            atomicAdd(myout + ei[EE + ebw + 32 + el] * 32 + l, acc1[i]);
            atomicAdd(myout + ei[EE + ebw + 64 + el] * 32 + l, acc2[i]);
            atomicAdd(myout + ei[EE + ebw + 96 + el] * 32 + l, acc3[i]);
        }
    }
}

extern "C" void kernel_launch(void* const* d_in, const int* in_sizes, int n_in,
                              void* d_out, int out_size, void* d_ws, size_t ws_size,
                              hipStream_t stream) {
    const float* x    = (const float*)d_in[0];
    const int*   ei   = (const int*)  d_in[1];
    const float* ea   = (const float*)d_in[2];
    const float* w1   = (const float*)d_in[3];
    const float* b1   = (const float*)d_in[4];
    const float* w2   = (const float*)d_in[5];
    const float* b2   = (const float*)d_in[6];
    const float* root = (const float*)d_in[7];
    const float* bias = (const float*)d_in[8];
    float* out = (float*)d_out;

    __bf16* w2p = (__bf16*)d_ws;                          // 262144 B
    __bf16* w1p = (__bf16*)((char*)d_ws + 262144);        //   8192 B
    __bf16* b2p = (__bf16*)((char*)d_ws + 270336);        //   2048 B
    const size_t partOff = 272384;
    const size_t one = 800000ull * sizeof(float);         // 3.2 MB per replica
    size_t avail = (ws_size > partOff) ? ws_size - partOff : 0;
    int nc = 0;
    for (int c = 8; c >= 1; c >>= 1)
        if ((size_t)c * one <= avail) { nc = c; break; }

    float* part = (float*)((char*)d_ws + partOff);
    if (nc > 0) {
        int nzero4 = nc * 200000;                         // float4 count
        int zb = (nzero4 + 255) / 256;
        prep_kernel<<<532 + zb, 256, 0, stream>>>(w1, w2, b2, w2p, w1p, b2p,
                                                  (float4*)part, nzero4);
        edge_kernel<<<(EE + 255) / 256, 128, 0, stream>>>(x, ei, ea, b1, w2p, w1p, b2p,
                                                          part, nc - 1);
        final_kernel<<<(NN * 32) / 256, 256, 0, stream>>>(x, root, bias, part, nc, out);
    } else {
        prep_kernel<<<532, 256, 0, stream>>>(w1, w2, b2, w2p, w1p, b2p, (float4*)part, 0);
        final_kernel<<<(NN * 32) / 256, 256, 0, stream>>>(x, root, bias, part, 0, out);
        edge_kernel<<<(EE + 255) / 256, 128, 0, stream>>>(x, ei, ea, b1, w2p, w1p, b2p,
                                                          out, 0);
    }
}

// Round 6
// 275.631 us; speedup vs baseline: 1.3746x; 1.3746x over previous
//
#include <hip/hip_runtime.h>
#include <hip/hip_fp16.h>

// NNConv on MI355X. msg[E x 32] = Z[E x 4096] @ w2r[4096 x 32],
// Z[e, c*32+i] = h[e,c]*xs[e,i] built on the fly in fp16 A-fragments via
// v_pk_mul_f16 (4 VALU/MFMA, no separate cvt). R4 skeleton: 4 waves x 64
// edges, persistent ea fragments, dbuf w2 chunks (1 barrier/chunk).
// Round 6: fp16 everywhere (accuracy UP vs bf16), 4-c chunks + u16 hT
// -> 32.75 KB LDS -> 4 blocks/CU (16 waves), phase-1 per-group to cap VGPRs.

#define NN 25000
#define EE 400000

typedef _Float16 f16x8 __attribute__((ext_vector_type(8)));
typedef float    f32x16 __attribute__((ext_vector_type(16)));

// ---------------- prep: pack w1/w2/b2 to fp16 fragment layout + zero replicas ----------------
__global__ __launch_bounds__(256) void prep_kernel(
    const float* __restrict__ w1, const float* __restrict__ w2,
    const float* __restrict__ b2,
    _Float16* __restrict__ w2p, _Float16* __restrict__ w1p, _Float16* __restrict__ b2p,
    float4* __restrict__ part4, int nzero4)
{
    int b = blockIdx.x;
    if (b < 532) {                       // 532*256 = 136192 pack threads, exact
        int t = b * 256 + threadIdx.x;
        if (t < 131072) {
            int j = t & 7, lane = (t >> 3) & 63, ih = (t >> 9) & 1, c = t >> 10;
            w2p[t] = (_Float16)w2[c * 1024 + (ih * 16 + ((lane >> 5) << 3) + j) * 32 + (lane & 31)];
        } else if (t < 135168) {
            int u = t - 131072;
            int j = u & 7, lane = (u >> 3) & 63, kk = (u >> 9) & 1, r = u >> 10;
            w1p[u] = (_Float16)w1[(kk * 16 + ((lane >> 5) << 3) + j) * 128 + r * 32 + (lane & 31)];
        } else {
            int u = t - 135168;
            int j = u & 7, lane = (u >> 3) & 63, ih = u >> 9;
            b2p[u] = (_Float16)b2[(ih * 16 + ((lane >> 5) << 3) + j) * 32 + (lane & 31)];
        }
    } else {
        int z = (b - 532) * 256 + threadIdx.x;
        if (z < nzero4) part4[z] = make_float4(0.f, 0.f, 0.f, 0.f);
    }
}

// ---------------- final: out = x@root + bias + sum(replicas) ----------------
__global__ __launch_bounds__(256) void final_kernel(
    const float* __restrict__ x, const float* __restrict__ root,
    const float* __restrict__ bias, const float* __restrict__ part,
    int ncopies, float* __restrict__ out)
{
    int gid = blockIdx.x * 256 + threadIdx.x;   // exactly NN*32
    int n = gid >> 5, o = gid & 31;
    float acc = bias[o];
    const float* xr = x + (n << 5);
#pragma unroll
    for (int i = 0; i < 32; ++i)
        acc = fmaf(xr[i], root[(i << 5) + o], acc);
    for (int c = 0; c < ncopies; ++c) acc += part[(size_t)c * 800000 + gid];
    out[gid] = acc;
}

// ---------------- fused MFMA edge kernel ----------------
// 256 thr = 4 waves x 64 edges (2 groups of 32) = 256 edges/block, 1563 blocks.
__global__ __launch_bounds__(256, 4) void edge_kernel(
    const float*    __restrict__ x,
    const int*      __restrict__ ei,
    const float*    __restrict__ ea,
    const float*    __restrict__ b1,
    const _Float16* __restrict__ w2p,
    const _Float16* __restrict__ w1p,
    const _Float16* __restrict__ b2p,
    float* __restrict__ outp, int copyMask)
{
    __shared__ __align__(16) _Float16 w2c[2][4096];        // 2 x 8 KB (4-c chunks)
    __shared__ unsigned short hTq[4][32][32][2];           // 16 KB: fp16 h per (row,l,group)

    const int t    = threadIdx.x;
    const int w    = t >> 6;
    const int lane = t & 63;
    const int l    = lane & 31;
    const int half = lane >> 5;

    const int  ebraw = blockIdx.x * 256 + w * 64;
    const bool live  = (ebraw + 64) <= EE;                 // wave-uniform
    const int  ebw   = live ? ebraw : (EE - 64);

    float* __restrict__ myout = outp + (size_t)(blockIdx.x & copyMask) * 800000;

    // ---- persistent edge-attr fragments (fp16), 2 groups ----
    union u8h { f16x8 v; __half2 h2[4]; };
    u8h eaf[2][2];
#pragma unroll
    for (int g = 0; g < 2; ++g)
#pragma unroll
        for (int kk = 0; kk < 2; ++kk) {
            const float* p = ea + (ebw + g * 32 + l) * 32 + kk * 16 + half * 8;
            float4 a0 = *(const float4*)p;
            float4 a1 = *(const float4*)(p + 4);
            eaf[g][kk].h2[0] = __float22half2_rn(make_float2(a0.x, a0.y));
            eaf[g][kk].h2[1] = __float22half2_rn(make_float2(a0.z, a0.w));
            eaf[g][kk].h2[2] = __float22half2_rn(make_float2(a1.x, a1.y));
            eaf[g][kk].h2[3] = __float22half2_rn(make_float2(a1.z, a1.w));
        }

    // ---- gather xs rows (fp16 pairs) for 2 groups ----
    __half2 xs0[8], xs1[8];
    {
        int s0 = ei[ebw + l], s1 = ei[ebw + 32 + l];
#pragma unroll
        for (int ih = 0; ih < 2; ++ih) {
            float4 a0 = *(const float4*)(x + s0 * 32 + ih * 16 + half * 8);
            float4 a1 = *(const float4*)(x + s0 * 32 + ih * 16 + half * 8 + 4);
            xs0[ih*4+0] = __float22half2_rn(make_float2(a0.x, a0.y));
            xs0[ih*4+1] = __float22half2_rn(make_float2(a0.z, a0.w));
            xs0[ih*4+2] = __float22half2_rn(make_float2(a1.x, a1.y));
            xs0[ih*4+3] = __float22half2_rn(make_float2(a1.z, a1.w));
            float4 c0 = *(const float4*)(x + s1 * 32 + ih * 16 + half * 8);
            float4 c1 = *(const float4*)(x + s1 * 32 + ih * 16 + half * 8 + 4);
            xs1[ih*4+0] = __float22half2_rn(make_float2(c0.x, c0.y));
            xs1[ih*4+1] = __float22half2_rn(make_float2(c0.z, c0.w));
            xs1[ih*4+2] = __float22half2_rn(make_float2(c1.x, c1.y));
            xs1[ih*4+3] = __float22half2_rn(make_float2(c1.z, c1.w));
        }
    }

    f32x16 acc0, acc1;
#pragma unroll
    for (int i = 0; i < 16; ++i) { acc0[i] = 0.f; acc1[i] = 0.f; }

    // ---- phase-1 slice for r: h[r*32..+32), one group at a time (VGPR cap) ----
    auto phase1 = [&](int r) {
        f16x8 w1f0 = *(const f16x8*)(w1p + ((r * 2 + 0) * 64 + lane) * 8);
        f16x8 w1f1 = *(const f16x8*)(w1p + ((r * 2 + 1) * 64 + lane) * 8);
        float bb[16];
#pragma unroll
        for (int i = 0; i < 16; ++i)
            bb[i] = b1[r * 32 + (i & 3) + ((i >> 2) << 3) + (half << 2)];
#pragma unroll
        for (int g = 0; g < 2; ++g) {
            f32x16 h;
#pragma unroll
            for (int i = 0; i < 16; ++i) h[i] = 0.f;
            h = __builtin_amdgcn_mfma_f32_32x32x16_f16(w1f0, eaf[g][0].v, h, 0, 0, 0);
            h = __builtin_amdgcn_mfma_f32_32x32x16_f16(w1f1, eaf[g][1].v, h, 0, 0, 0);
#pragma unroll
            for (int i = 0; i < 16; ++i) {
                int row = (i & 3) + ((i >> 2) << 3) + (half << 2);   // verified C/D map
                __half hv = __float2half(fmaxf(h[i] + bb[i], 0.f));
                hTq[w][row][l][g] = __half_as_ushort(hv);            // wave-private
            }
        }
    };

    // ---- w2 chunk pipeline prologue: chunk0 -> buf0, pf holds chunk1 ----
    const char* w2g = (const char*)w2p;
    float4 pf[2];
#pragma unroll
    for (int s = 0; s < 2; ++s)
        pf[s] = *(const float4*)(w2g + (t + s * 256) * 16);
#pragma unroll
    for (int s = 0; s < 2; ++s)
        ((float4*)w2c[0])[t + s * 256] = pf[s];
#pragma unroll
    for (int s = 0; s < 2; ++s)
        pf[s] = *(const float4*)(w2g + 8192 + (t + s * 256) * 16);
    phase1(0);
    __syncthreads();

    // chunk body: write pf(cc+1)->WB, issue pf loads (cc+2), compute RB, barrier
    auto chunk = [&](int cc, const _Float16* RB, _Float16* WBp) {
        if (cc < 31) {
            float4* WB = (float4*)WBp;
#pragma unroll
            for (int s = 0; s < 2; ++s) WB[t + s * 256] = pf[s];
        }
        if (cc < 30) {
#pragma unroll
            for (int s = 0; s < 2; ++s)
                pf[s] = *(const float4*)(w2g + (cc + 2) * 8192 + (t + s * 256) * 16);
        }
#pragma unroll
        for (int cl = 0; cl < 4; ++cl) {
            unsigned u = *(const unsigned*)&hTq[w][((cc & 7) << 2) + cl][l][0];
            __half2 hp = *reinterpret_cast<const __half2*>(&u);
            __half2 h0 = __half2half2(__low2half(hp));     // dup for group 0
            __half2 h1 = __half2half2(__high2half(hp));    // dup for group 1
#pragma unroll
            for (int ih = 0; ih < 2; ++ih) {
                f16x8 bfr = *(const f16x8*)(RB + (((cl << 1) + ih) * 64 + lane) * 8);
                u8h A;
#pragma unroll
                for (int p = 0; p < 4; ++p)
                    A.h2[p] = __hmul2(h0, xs0[ih * 4 + p]);    // v_pk_mul_f16
                acc0 = __builtin_amdgcn_mfma_f32_32x32x16_f16(A.v, bfr, acc0, 0, 0, 0);
#pragma unroll
                for (int p = 0; p < 4; ++p)
                    A.h2[p] = __hmul2(h1, xs1[ih * 4 + p]);
                acc1 = __builtin_amdgcn_mfma_f32_32x32x16_f16(A.v, bfr, acc1, 0, 0, 0);
            }
        }
        __syncthreads();
    };

#pragma unroll 1
    for (int r = 0; r < 4; ++r) {
        if (r > 0) phase1(r);                 // wave-private hTq: no barrier needed
        chunk(r * 8 + 0, w2c[0], w2c[1]);
        chunk(r * 8 + 1, w2c[1], w2c[0]);
        chunk(r * 8 + 2, w2c[0], w2c[1]);
        chunk(r * 8 + 3, w2c[1], w2c[0]);
        chunk(r * 8 + 4, w2c[0], w2c[1]);
        chunk(r * 8 + 5, w2c[1], w2c[0]);
        chunk(r * 8 + 6, w2c[0], w2c[1]);
        chunk(r * 8 + 7, w2c[1], w2c[0]);
    }

    // ---- b2 contribution: extra K-step with h == 1 (A-fragment = xs, no VALU) ----
#pragma unroll
    for (int ih = 0; ih < 2; ++ih) {
        f16x8 bfr = *(const f16x8*)(b2p + (ih * 64 + lane) * 8);
        u8h A;
#pragma unroll
        for (int p = 0; p < 4; ++p) A.h2[p] = xs0[ih * 4 + p];
        acc0 = __builtin_amdgcn_mfma_f32_32x32x16_f16(A.v, bfr, acc0, 0, 0, 0);
#pragma unroll
        for (int p = 0; p < 4; ++p) A.h2[p] = xs1[ih * 4 + p];
        acc1 = __builtin_amdgcn_mfma_f32_32x32x16_f16(A.v, bfr, acc1, 0, 0, 0);
    }

    // ---- scatter into this block's replica (skip for clamped tail waves) ----
    if (live) {
#pragma unroll
        for (int i = 0; i < 16; ++i) {
            int el = (i & 3) + ((i >> 2) << 3) + (half << 2);
            atomicAdd(myout + ei[EE + ebw +      el] * 32 + l, acc0[i]);
            atomicAdd(myout + ei[EE + ebw + 32 + el] * 32 + l, acc1[i]);
        }
    }
}

extern "C" void kernel_launch(void* const* d_in, const int* in_sizes, int n_in,
                              void* d_out, int out_size, void* d_ws, size_t ws_size,
                              hipStream_t stream) {
    const float* x    = (const float*)d_in[0];
    const int*   ei   = (const int*)  d_in[1];
    const float* ea   = (const float*)d_in[2];
    const float* w1   = (const float*)d_in[3];
    const float* b1   = (const float*)d_in[4];
    const float* w2   = (const float*)d_in[5];
    const float* b2   = (const float*)d_in[6];
    const float* root = (const float*)d_in[7];
    const float* bias = (const float*)d_in[8];
    float* out = (float*)d_out;

    _Float16* w2p = (_Float16*)d_ws;                      // 262144 B
    _Float16* w1p = (_Float16*)((char*)d_ws + 262144);    //   8192 B
    _Float16* b2p = (_Float16*)((char*)d_ws + 270336);    //   2048 B
    const size_t partOff = 272384;
    const size_t one = 800000ull * sizeof(float);         // 3.2 MB per replica
    size_t avail = (ws_size > partOff) ? ws_size - partOff : 0;
    int nc = 0;
    for (int c = 8; c >= 1; c >>= 1)
        if ((size_t)c * one <= avail) { nc = c; break; }

    float* part = (float*)((char*)d_ws + partOff);
    if (nc > 0) {
        int nzero4 = nc * 200000;                         // float4 count
        int zb = (nzero4 + 255) / 256;
        prep_kernel<<<532 + zb, 256, 0, stream>>>(w1, w2, b2, w2p, w1p, b2p,
                                                  (float4*)part, nzero4);
        edge_kernel<<<(EE + 255) / 256, 256, 0, stream>>>(x, ei, ea, b1, w2p, w1p, b2p,
                                                          part, nc - 1);
        final_kernel<<<(NN * 32) / 256, 256, 0, stream>>>(x, root, bias, part, nc, out);
    } else {
        prep_kernel<<<532, 256, 0, stream>>>(w1, w2, b2, w2p, w1p, b2p, (float4*)part, 0);
        final_kernel<<<(NN * 32) / 256, 256, 0, stream>>>(x, root, bias, part, 0, out);
        edge_kernel<<<(EE + 255) / 256, 256, 0, stream>>>(x, ei, ea, b1, w2p, w1p, b2p,
                                                          out, 0);
    }
}